// Round 3
// baseline (497.395 us; speedup 1.0000x reference)
//
#include <hip/hip_runtime.h>

#define U_   8
#define B_   16384
#define NC_  62

typedef __attribute__((ext_vector_type(8))) short bfrag;   // 8 bf16 (4 VGPRs)
typedef __attribute__((ext_vector_type(4))) float facc;    // 4 fp32 acc

__device__ __forceinline__ float bf2f(unsigned int lo16) {
    union { unsigned int i; float f; } v;
    v.i = lo16 << 16;
    return v.f;
}
__device__ __forceinline__ unsigned short f2bf(float f) {
    unsigned int x = __float_as_uint(f);
    return (unsigned short)((x + 0x7fffu + ((x >> 16) & 1u)) >> 16);
}

// ---------------------------------------------------------------------------
// prep: normalized policies, final per-unit weights, folded output bias
// ---------------------------------------------------------------------------
__global__ void prep_kernel(const float* __restrict__ p1, const float* __restrict__ p2,
                            const float* __restrict__ pf, const float* __restrict__ b2,
                            float* __restrict__ P1n, float* __restrict__ P2n,
                            float* __restrict__ wfin, float* __restrict__ cconst)
{
    int t = threadIdx.x;
    if (t >= 64) return;
    int row = t >> 3;
    float s1 = 0.f, s2 = 0.f;
    for (int f = 0; f < 8; f++) { s1 += p1[row * 8 + f]; s2 += p2[row * 8 + f]; }
    P1n[t] = p1[t] * (s1 > 0.f ? 1.f / s1 : 1.f);
    P2n[t] = p2[t] * (s2 > 0.f ? 1.f / s2 : 1.f);
    float d = 0.f;
    for (int j = 0; j < 8; j++) d += pf[j];
    float inv = d > 0.f ? 1.f / d : 1.f;
    float wv[8];
    for (int j = 0; j < 8; j++) {
        float v = pf[j];
        for (int i = j; i < 8; i++) v *= inv;   // inv applied (8-j) times
        wv[j] = v;
    }
    if (t < 8) wfin[t] = wv[t];
    float cc = 0.f;
    if (t < NC_) for (int u = 0; u < 8; u++) cc += wv[u] * b2[u * NC_ + t];
    cconst[t] = cc;
}

// ---------------------------------------------------------------------------
// reorder_w0: W0 [u][k=512][n=512] fp32 -> W0r[n'][k] bf16,
//             n' = (n>>3)*64 + u*8 + (n&7)   (64-col groups: 8 units x 8 feats)
// ---------------------------------------------------------------------------
__global__ __launch_bounds__(256) void reorder_w0(
    const float* __restrict__ W0, unsigned short* __restrict__ W0r)
{
    __shared__ float tile[32][33];
    const int u  = blockIdx.z;
    const int n0 = blockIdx.x * 32, k0 = blockIdx.y * 32;
    const int tx = threadIdx.x & 31, ty = threadIdx.x >> 5;
    const float* Wb = W0 + (long)u * 512 * 512;
#pragma unroll
    for (int i = 0; i < 4; i++)
        tile[ty + i * 8][tx] = Wb[(long)(k0 + ty + i * 8) * 512 + n0 + tx];
    __syncthreads();
#pragma unroll
    for (int i = 0; i < 4; i++) {
        int n = n0 + ty + i * 8, k = k0 + tx;
        int np = (n >> 3) * 64 + u * 8 + (n & 7);
        W0r[(long)np * 512 + k] = f2bf(tile[tx][ty + i * 8]);
    }
}

// ---------------------------------------------------------------------------
// transpose_w: W [u][k=512][n=512] fp32 -> Wt [u][n][k] bf16
// ---------------------------------------------------------------------------
__global__ __launch_bounds__(256) void transpose_w(
    const float* __restrict__ W, unsigned short* __restrict__ Wt)
{
    __shared__ float tile[32][33];
    const int u  = blockIdx.z;
    const int n0 = blockIdx.x * 32, k0 = blockIdx.y * 32;
    const int tx = threadIdx.x & 31, ty = threadIdx.x >> 5;
    const float* Wb = W + (long)u * 512 * 512;
#pragma unroll
    for (int i = 0; i < 4; i++)
        tile[ty + i * 8][tx] = Wb[(long)(k0 + ty + i * 8) * 512 + n0 + tx];
    __syncthreads();
    unsigned short* Wo = Wt + (long)u * 512 * 512;
#pragma unroll
    for (int i = 0; i < 4; i++) {
        int n = n0 + ty + i * 8, k = k0 + tx;
        Wo[(long)n * 512 + k] = f2bf(tile[tx][ty + i * 8]);
    }
}

// ---------------------------------------------------------------------------
// wout_build: Woutt[c][f*512+k] = sum_u wfin[u]*P2n[u,f]*W2[u][k][c]  (c<62)
// ---------------------------------------------------------------------------
__global__ __launch_bounds__(256) void wout_build(
    const float* __restrict__ W2, const float* __restrict__ P2n,
    const float* __restrict__ wfin, unsigned short* __restrict__ Woutt)
{
    const int c   = threadIdx.x & 63;
    const int row = blockIdx.x * 4 + (threadIdx.x >> 6);   // [0,4096)
    const int f = row >> 9, k = row & 511;
    float s = 0.f;
    if (c < NC_) {
#pragma unroll
        for (int u = 0; u < 8; u++)
            s += wfin[u] * P2n[u * 8 + f] * W2[((long)u * 512 + k) * NC_ + c];
    }
    Woutt[(long)c * 4096 + row] = f2bf(s);
}

// ---------------------------------------------------------------------------
// x fp32 -> bf16, 8 elems/thread
// ---------------------------------------------------------------------------
__global__ __launch_bounds__(256) void convert_x(
    const float* __restrict__ x, unsigned short* __restrict__ xb, long n)
{
    long i = ((long)blockIdx.x * 256 + threadIdx.x) * 8;
    if (i >= n) return;
    const float4* xp = (const float4*)(x + i);
    float4 a = xp[0], b = xp[1];
    uint4 o;
    o.x = f2bf(a.x) | ((unsigned)f2bf(a.y) << 16);
    o.y = f2bf(a.z) | ((unsigned)f2bf(a.w) << 16);
    o.z = f2bf(b.x) | ((unsigned)f2bf(b.y) << 16);
    o.w = f2bf(b.z) | ((unsigned)f2bf(b.w) << 16);
    *(uint4*)(xb + i) = o;
}

// ---------------------------------------------------------------------------
// gemm0_mix v2: weights-stationary, barrier-free K-loop.
// Block: 256 rows x 64 cols (g-group: 8 units x 8 feats), K=512.
// B tile (64x512 bf16 = 64 KB) staged once in slab-major LDS; A streamed
// into VGPRs with 2-slab prefetch. Epilogue: relu+bias tile -> LDS, mix with
// P1n intra-block, write a1cat [row][4096] as 16-B granules.
// ---------------------------------------------------------------------------
__global__ __launch_bounds__(256, 2) void gemm0_mix(
    const unsigned short* __restrict__ xb, const unsigned short* __restrict__ W0r,
    const float* __restrict__ b0, const float* __restrict__ P1n,
    unsigned short* __restrict__ a1)
{
    __shared__ __align__(16) unsigned short sB[16 * 2048];   // 64 KB
    const int tid = threadIdx.x, w = tid >> 6, lane = tid & 63;
    const int flat = blockIdx.x;
    const int xcd = flat & 7, seq = flat >> 3;
    const int g = xcd * 8 + (seq & 7);          // feature-group per XCD
    const long mBase = (long)(seq >> 3) * 256;

    // stage B (W0r rows g*64..g*64+63) into slab-major LDS
    const unsigned short* Bg = W0r + (long)g * 64 * 512;
#pragma unroll
    for (int i = 0; i < 16; i++) {
        const int c = i * 256 + tid;
        const int n = c >> 6, k = (c & 63) * 8;
        uint4 v = *(const uint4*)(Bg + (long)n * 512 + k);
        *(uint4*)(sB + (k >> 5) * 2048 + n * 32 + (k & 31)) = v;
    }

    const int r = lane & 15, q = lane >> 4;
    const unsigned short* Ap[4];
#pragma unroll
    for (int mt = 0; mt < 4; mt++)
        Ap[mt] = xb + (mBase + w * 64 + mt * 16 + r) * 512 + q * 8;

    __syncthreads();

    facc acc[4][4];
#pragma unroll
    for (int i = 0; i < 4; i++)
#pragma unroll
        for (int j = 0; j < 4; j++) acc[i][j] = (facc){0.f, 0.f, 0.f, 0.f};

    bfrag aCur[4], aNxt[4];
#pragma unroll
    for (int mt = 0; mt < 4; mt++) aCur[mt] = *(const bfrag*)(Ap[mt]);
#pragma unroll
    for (int mt = 0; mt < 4; mt++) aNxt[mt] = *(const bfrag*)(Ap[mt] + 32);

#pragma unroll
    for (int s = 0; s < 16; s++) {
        bfrag aF[4];
#pragma unroll
        for (int mt = 0; mt < 4; mt++) { aF[mt] = aCur[mt]; aCur[mt] = aNxt[mt]; }
        if (s < 14) {
#pragma unroll
            for (int mt = 0; mt < 4; mt++)
                aNxt[mt] = *(const bfrag*)(Ap[mt] + (s + 2) * 32);
        }
        bfrag bF[4];
#pragma unroll
        for (int nt = 0; nt < 4; nt++)
            bF[nt] = *(const bfrag*)(sB + s * 2048 + (nt * 16 + r) * 32 + q * 8);
#pragma unroll
        for (int mt = 0; mt < 4; mt++)
#pragma unroll
            for (int nt = 0; nt < 4; nt++)
                acc[mt][nt] = __builtin_amdgcn_mfma_f32_16x16x32_bf16(
                    aF[mt], bF[nt], acc[mt][nt], 0, 0, 0);
    }

    __syncthreads();   // all waves done reading B; reuse sB as h0 tile [256][72]
#pragma unroll
    for (int nt = 0; nt < 4; nt++) {
        const int cl = nt * 16 + r;            // u = cl>>3, j = cl&7
        const float bv = b0[(cl >> 3) * 512 + g * 8 + (cl & 7)];
#pragma unroll
        for (int mt = 0; mt < 4; mt++) {
            const int rl = w * 64 + mt * 16 + q * 4;
#pragma unroll
            for (int rg = 0; rg < 4; rg++) {
                float v = acc[mt][nt][rg] + bv;
                v = v > 0.f ? v : 0.f;
                sB[(rl + rg) * 72 + cl] = f2bf(v);
            }
        }
    }
    __syncthreads();

    // mix: thread = one row; o[t][j] = sum_u P1n[t,u] * h0[u][j]
    float pw[64];
#pragma unroll
    for (int i = 0; i < 64; i++) pw[i] = P1n[i];   // uniform -> scalar regs
    const int row = tid;
    float h[64];
#pragma unroll
    for (int i = 0; i < 8; i++) {
        bfrag hv = *(const bfrag*)(sB + row * 72 + i * 8);
#pragma unroll
        for (int j = 0; j < 8; j++)
            h[i * 8 + j] = bf2f((unsigned int)(unsigned short)hv[j]);
    }
    unsigned short* orow = a1 + (mBase + row) * 4096 + g * 8;
#pragma unroll
    for (int t = 0; t < 8; t++) {
        float o[8];
#pragma unroll
        for (int j = 0; j < 8; j++) {
            float s = 0.f;
#pragma unroll
            for (int u = 0; u < 8; u++) s = fmaf(pw[t * 8 + u], h[u * 8 + j], s);
            o[j] = s;
        }
        uint4 ov;
        ov.x = f2bf(o[0]) | ((unsigned)f2bf(o[1]) << 16);
        ov.y = f2bf(o[2]) | ((unsigned)f2bf(o[3]) << 16);
        ov.z = f2bf(o[4]) | ((unsigned)f2bf(o[5]) << 16);
        ov.w = f2bf(o[6]) | ((unsigned)f2bf(o[7]) << 16);
        *(uint4*)(orow + t * 512) = ov;
    }
}

// ---------------------------------------------------------------------------
// gemm_h v2: weights-stationary, barrier-free. Unit u = XCD (weights L2-resident).
// Block: 256 rows x 64 cols, K=512. h1cat[row][u*512+col] = relu(a1[u]@W1t[u]+b1).
// ---------------------------------------------------------------------------
__global__ __launch_bounds__(256, 2) void gemm_h(
    const unsigned short* __restrict__ A,      // a1cat [rows][4096]
    const unsigned short* __restrict__ W1t,    // [u][n][k]
    const float* __restrict__ b1,
    unsigned short* __restrict__ C)            // h1cat [rows][4096]
{
    __shared__ __align__(16) unsigned short sB[16 * 2048];   // 64 KB
    const int tid = threadIdx.x, w = tid >> 6, lane = tid & 63;
    const int flat = blockIdx.x;
    const int u = flat & 7, seq = flat >> 3;
    const int nBase = (seq & 7) * 64;                // n inner -> A L2-reuse
    const long mBase = (long)(seq >> 3) * 256;

    const unsigned short* Bg = W1t + ((long)u * 512 + nBase) * 512;
#pragma unroll
    for (int i = 0; i < 16; i++) {
        const int c = i * 256 + tid;
        const int n = c >> 6, k = (c & 63) * 8;
        uint4 v = *(const uint4*)(Bg + (long)n * 512 + k);
        *(uint4*)(sB + (k >> 5) * 2048 + n * 32 + (k & 31)) = v;
    }

    const int r = lane & 15, q = lane >> 4;
    const unsigned short* Ap[4];
#pragma unroll
    for (int mt = 0; mt < 4; mt++)
        Ap[mt] = A + (mBase + w * 64 + mt * 16 + r) * 4096 + u * 512 + q * 8;

    __syncthreads();

    facc acc[4][4];
#pragma unroll
    for (int i = 0; i < 4; i++)
#pragma unroll
        for (int j = 0; j < 4; j++) acc[i][j] = (facc){0.f, 0.f, 0.f, 0.f};

    bfrag aCur[4], aNxt[4];
#pragma unroll
    for (int mt = 0; mt < 4; mt++) aCur[mt] = *(const bfrag*)(Ap[mt]);
#pragma unroll
    for (int mt = 0; mt < 4; mt++) aNxt[mt] = *(const bfrag*)(Ap[mt] + 32);

#pragma unroll
    for (int s = 0; s < 16; s++) {
        bfrag aF[4];
#pragma unroll
        for (int mt = 0; mt < 4; mt++) { aF[mt] = aCur[mt]; aCur[mt] = aNxt[mt]; }
        if (s < 14) {
#pragma unroll
            for (int mt = 0; mt < 4; mt++)
                aNxt[mt] = *(const bfrag*)(Ap[mt] + (s + 2) * 32);
        }
        bfrag bF[4];
#pragma unroll
        for (int nt = 0; nt < 4; nt++)
            bF[nt] = *(const bfrag*)(sB + s * 2048 + (nt * 16 + r) * 32 + q * 8);
#pragma unroll
        for (int mt = 0; mt < 4; mt++)
#pragma unroll
            for (int nt = 0; nt < 4; nt++)
                acc[mt][nt] = __builtin_amdgcn_mfma_f32_16x16x32_bf16(
                    aF[mt], bF[nt], acc[mt][nt], 0, 0, 0);
    }

#pragma unroll
    for (int nt = 0; nt < 4; nt++) {
        const int col = nBase + nt * 16 + r;
        const float bv = b1[u * 512 + col];
#pragma unroll
        for (int mt = 0; mt < 4; mt++) {
#pragma unroll
            for (int rg = 0; rg < 4; rg++) {
                const long gm = mBase + w * 64 + mt * 16 + q * 4 + rg;
                float v = acc[mt][nt][rg] + bv;
                v = v > 0.f ? v : 0.f;
                C[gm * 4096 + u * 512 + col] = f2bf(v);
            }
        }
    }
}

// ---------------------------------------------------------------------------
// gemm_out v2: split-K (kc = unit = XCD), weights-stationary, barrier-free.
// Block: 128 rows x 64 cols, K-window = kc*512..+512. Writes fp32 partials.
// ---------------------------------------------------------------------------
__global__ __launch_bounds__(256, 2) void gemm_out(
    const unsigned short* __restrict__ A,      // h1cat [rows][4096]
    const unsigned short* __restrict__ Bt,     // Woutt [64 c][4096]
    float* __restrict__ partial, int Bc)
{
    __shared__ __align__(16) unsigned short sB[16 * 2048];   // 64 KB
    const int tid = threadIdx.x, w = tid >> 6, lane = tid & 63;
    const int flat = blockIdx.x;
    const int kc = flat & 7;
    const long mBase = (long)(flat >> 3) * 128;

#pragma unroll
    for (int i = 0; i < 16; i++) {
        const int c = i * 256 + tid;
        const int n = c >> 6, k = (c & 63) * 8;
        uint4 v = *(const uint4*)(Bt + (long)n * 4096 + kc * 512 + k);
        *(uint4*)(sB + (k >> 5) * 2048 + n * 32 + (k & 31)) = v;
    }

    const int r = lane & 15, q = lane >> 4;
    const unsigned short* Ap[2];
#pragma unroll
    for (int mt = 0; mt < 2; mt++)
        Ap[mt] = A + (mBase + w * 32 + mt * 16 + r) * 4096 + kc * 512 + q * 8;

    __syncthreads();

    facc acc[2][4];
#pragma unroll
    for (int i = 0; i < 2; i++)
#pragma unroll
        for (int j = 0; j < 4; j++) acc[i][j] = (facc){0.f, 0.f, 0.f, 0.f};

    bfrag aCur[2], aNxt[2];
#pragma unroll
    for (int mt = 0; mt < 2; mt++) aCur[mt] = *(const bfrag*)(Ap[mt]);
#pragma unroll
    for (int mt = 0; mt < 2; mt++) aNxt[mt] = *(const bfrag*)(Ap[mt] + 32);

#pragma unroll
    for (int s = 0; s < 16; s++) {
        bfrag aF[2];
#pragma unroll
        for (int mt = 0; mt < 2; mt++) { aF[mt] = aCur[mt]; aCur[mt] = aNxt[mt]; }
        if (s < 14) {
#pragma unroll
            for (int mt = 0; mt < 2; mt++)
                aNxt[mt] = *(const bfrag*)(Ap[mt] + (s + 2) * 32);
        }
        bfrag bF[4];
#pragma unroll
        for (int nt = 0; nt < 4; nt++)
            bF[nt] = *(const bfrag*)(sB + s * 2048 + (nt * 16 + r) * 32 + q * 8);
#pragma unroll
        for (int mt = 0; mt < 2; mt++)
#pragma unroll
            for (int nt = 0; nt < 4; nt++)
                acc[mt][nt] = __builtin_amdgcn_mfma_f32_16x16x32_bf16(
                    aF[mt], bF[nt], acc[mt][nt], 0, 0, 0);
    }

    float* pb = partial + (long)kc * Bc * 64;
#pragma unroll
    for (int nt = 0; nt < 4; nt++) {
        const int col = nt * 16 + r;
#pragma unroll
        for (int mt = 0; mt < 2; mt++) {
#pragma unroll
            for (int rg = 0; rg < 4; rg++) {
                const long gm = mBase + w * 32 + mt * 16 + q * 4 + rg;
                pb[gm * 64 + col] = acc[mt][nt][rg];
            }
        }
    }
}

// ---------------------------------------------------------------------------
// reduce_out: out[row][c] = sum_kc partial[kc][row][c] + cconst[c]
// ---------------------------------------------------------------------------
__global__ __launch_bounds__(256) void reduce_out(
    const float* __restrict__ partial, const float* __restrict__ cconst,
    float* __restrict__ out, int Bc)
{
    const long flat = (long)blockIdx.x * 256 + threadIdx.x;
    const long row = flat >> 2;
    const int cg = (int)(flat & 3) * 16;
    float s[16];
#pragma unroll
    for (int j = 0; j < 16; j++) s[j] = 0.f;
#pragma unroll
    for (int kc = 0; kc < 8; kc++) {
        const float4* p = (const float4*)(partial + ((long)kc * Bc + row) * 64 + cg);
#pragma unroll
        for (int v4 = 0; v4 < 4; v4++) {
            float4 v = p[v4];
            s[v4 * 4 + 0] += v.x; s[v4 * 4 + 1] += v.y;
            s[v4 * 4 + 2] += v.z; s[v4 * 4 + 3] += v.w;
        }
    }
#pragma unroll
    for (int j = 0; j < 16; j++) {
        const int c = cg + j;
        if (c < NC_) out[row * NC_ + c] = s[j] + cconst[c];
    }
}

// ---------------------------------------------------------------------------
extern "C" void kernel_launch(void* const* d_in, const int* in_sizes, int n_in,
                              void* d_out, int out_size, void* d_ws, size_t ws_size,
                              hipStream_t stream)
{
    const float* x  = (const float*)d_in[0];
    const float* p1 = (const float*)d_in[1];
    const float* p2 = (const float*)d_in[2];
    const float* pf = (const float*)d_in[3];
    const float* W0 = (const float*)d_in[4];
    const float* b0 = (const float*)d_in[5];
    const float* W1 = (const float*)d_in[6];
    const float* b1 = (const float*)d_in[7];
    const float* W2 = (const float*)d_in[8];
    const float* b2 = (const float*)d_in[9];
    float* out = (float*)d_out;

    char* ws = (char*)d_ws;
    size_t off = 0;
    auto alloc = [&](size_t bytes) -> void* {
        void* p = ws + off;
        off += (bytes + 255) & ~(size_t)255;
        return p;
    };
    float* P1n    = (float*)alloc(64 * sizeof(float));
    float* P2n    = (float*)alloc(64 * sizeof(float));
    float* wfin   = (float*)alloc(8 * sizeof(float));
    float* cconst = (float*)alloc(64 * sizeof(float));
    unsigned short* W0r   = (unsigned short*)alloc((size_t)4096 * 512 * 2);
    unsigned short* W1t   = (unsigned short*)alloc((size_t)U_ * 512 * 512 * 2);
    unsigned short* Woutt = (unsigned short*)alloc((size_t)64 * 4096 * 2);
    unsigned short* xb    = (unsigned short*)alloc((size_t)B_ * 512 * 2);

    // chunk size: a1 + h1 (bf16, Bc x 4096) + partial (fp32, 8 x Bc x 64)
    size_t remain = ws_size > off ? ws_size - off : 0;
    int Bc = 2048;
    for (int cand = B_; cand >= 2048; cand >>= 1) {
        size_t need = 2ull * cand * 4096 * 2 + 8ull * cand * 64 * 4 + 1024;
        if (need <= remain) { Bc = cand; break; }
    }
    unsigned short* a1   = (unsigned short*)alloc((size_t)Bc * 4096 * 2);
    unsigned short* h1   = (unsigned short*)alloc((size_t)Bc * 4096 * 2);
    float* partial       = (float*)alloc(8ull * Bc * 64 * 4);

    prep_kernel<<<1, 64, 0, stream>>>(p1, p2, pf, b2, P1n, P2n, wfin, cconst);
    reorder_w0<<<dim3(16, 16, 8), 256, 0, stream>>>(W0, W0r);
    transpose_w<<<dim3(16, 16, 8), 256, 0, stream>>>(W1, W1t);
    wout_build<<<dim3(1024), 256, 0, stream>>>(W2, P2n, wfin, Woutt);
    convert_x<<<dim3(B_ * 512 / 8 / 256), 256, 0, stream>>>(x, xb, (long)B_ * 512);

    const int Mb = Bc / 256;
    for (int bb = 0; bb < B_; bb += Bc) {
        gemm0_mix<<<dim3(64 * Mb), 256, 0, stream>>>(
            xb + (long)bb * 512, W0r, b0, P1n, a1);
        gemm_h<<<dim3(64 * Mb), 256, 0, stream>>>(a1, W1t, b1, h1);
        gemm_out<<<dim3(8 * (Bc / 128)), 256, 0, stream>>>(h1, Woutt, partial, Bc);
        reduce_out<<<dim3(Bc / 64), 256, 0, stream>>>(
            partial, cconst, out + (long)bb * NC_, Bc);
    }
}

// Round 4
// 327.121 us; speedup vs baseline: 1.5205x; 1.5205x over previous
//
#include <hip/hip_runtime.h>

#define U_   8
#define B_   16384
#define NC_  62

typedef __attribute__((ext_vector_type(8))) short bfrag;   // 8 bf16 (4 VGPRs)
typedef __attribute__((ext_vector_type(4))) float facc;    // 4 fp32 acc

__device__ __forceinline__ float bf2f(unsigned int lo16) {
    union { unsigned int i; float f; } v;
    v.i = lo16 << 16;
    return v.f;
}
__device__ __forceinline__ unsigned short f2bf(float f) {
    unsigned int x = __float_as_uint(f);
    return (unsigned short)((x + 0x7fffu + ((x >> 16) & 1u)) >> 16);
}
__device__ __forceinline__ void gl2lds16(const void* g, void* l) {
    __builtin_amdgcn_global_load_lds(
        (const __attribute__((address_space(1))) void*)g,
        (__attribute__((address_space(3))) void*)l, 16, 0, 0);
}

// ---------------------------------------------------------------------------
// prep: normalized policies, final per-unit weights, folded output bias
// ---------------------------------------------------------------------------
__global__ void prep_kernel(const float* __restrict__ p1, const float* __restrict__ p2,
                            const float* __restrict__ pf, const float* __restrict__ b2,
                            float* __restrict__ P1n, float* __restrict__ P2n,
                            float* __restrict__ wfin, float* __restrict__ cconst)
{
    int t = threadIdx.x;
    if (t >= 64) return;
    int row = t >> 3;
    float s1 = 0.f, s2 = 0.f;
    for (int f = 0; f < 8; f++) { s1 += p1[row * 8 + f]; s2 += p2[row * 8 + f]; }
    P1n[t] = p1[t] * (s1 > 0.f ? 1.f / s1 : 1.f);
    P2n[t] = p2[t] * (s2 > 0.f ? 1.f / s2 : 1.f);
    float d = 0.f;
    for (int j = 0; j < 8; j++) d += pf[j];
    float inv = d > 0.f ? 1.f / d : 1.f;
    float wv[8];
    for (int j = 0; j < 8; j++) {
        float v = pf[j];
        for (int i = j; i < 8; i++) v *= inv;   // inv applied (8-j) times
        wv[j] = v;
    }
    if (t < 8) wfin[t] = wv[t];
    float cc = 0.f;
    if (t < NC_) for (int u = 0; u < 8; u++) cc += wv[u] * b2[u * NC_ + t];
    cconst[t] = cc;
}

// ---------------------------------------------------------------------------
// reorder_w0: W0 [u][k=512][n=512] fp32 -> W0r[n'][k] bf16,
//             n' = (n>>5)*256 + u*32 + (n&31)   (256-col groups: 8u x 32f)
// ---------------------------------------------------------------------------
__global__ __launch_bounds__(256) void reorder_w0(
    const float* __restrict__ W0, unsigned short* __restrict__ W0r)
{
    __shared__ float tile[32][33];
    const int u  = blockIdx.z;
    const int n0 = blockIdx.x * 32, k0 = blockIdx.y * 32;
    const int tx = threadIdx.x & 31, ty = threadIdx.x >> 5;
    const float* Wb = W0 + (long)u * 512 * 512;
#pragma unroll
    for (int i = 0; i < 4; i++)
        tile[ty + i * 8][tx] = Wb[(long)(k0 + ty + i * 8) * 512 + n0 + tx];
    __syncthreads();
#pragma unroll
    for (int i = 0; i < 4; i++) {
        int n = n0 + ty + i * 8, k = k0 + tx;
        int np = (n >> 5) * 256 + u * 32 + (n & 31);
        W0r[(long)np * 512 + k] = f2bf(tile[tx][ty + i * 8]);
    }
}

// ---------------------------------------------------------------------------
// transpose_w: W [u][k=512][n=512] fp32 -> Wt [u][n][k] bf16
// ---------------------------------------------------------------------------
__global__ __launch_bounds__(256) void transpose_w(
    const float* __restrict__ W, unsigned short* __restrict__ Wt)
{
    __shared__ float tile[32][33];
    const int u  = blockIdx.z;
    const int n0 = blockIdx.x * 32, k0 = blockIdx.y * 32;
    const int tx = threadIdx.x & 31, ty = threadIdx.x >> 5;
    const float* Wb = W + (long)u * 512 * 512;
#pragma unroll
    for (int i = 0; i < 4; i++)
        tile[ty + i * 8][tx] = Wb[(long)(k0 + ty + i * 8) * 512 + n0 + tx];
    __syncthreads();
    unsigned short* Wo = Wt + (long)u * 512 * 512;
#pragma unroll
    for (int i = 0; i < 4; i++) {
        int n = n0 + ty + i * 8, k = k0 + tx;
        Wo[(long)n * 512 + k] = f2bf(tile[tx][ty + i * 8]);
    }
}

// ---------------------------------------------------------------------------
// wout_build: Woutt[c][f*512+k] = sum_u wfin[u]*P2n[u,f]*W2[u][k][c]  (c<62)
// ---------------------------------------------------------------------------
__global__ __launch_bounds__(256) void wout_build(
    const float* __restrict__ W2, const float* __restrict__ P2n,
    const float* __restrict__ wfin, unsigned short* __restrict__ Woutt)
{
    const int c   = threadIdx.x & 63;
    const int row = blockIdx.x * 4 + (threadIdx.x >> 6);   // [0,4096)
    const int f = row >> 9, k = row & 511;
    float s = 0.f;
    if (c < NC_) {
#pragma unroll
        for (int u = 0; u < 8; u++)
            s += wfin[u] * P2n[u * 8 + f] * W2[((long)u * 512 + k) * NC_ + c];
    }
    Woutt[(long)c * 4096 + row] = f2bf(s);
}

// ---------------------------------------------------------------------------
// x fp32 -> bf16, 8 elems/thread
// ---------------------------------------------------------------------------
__global__ __launch_bounds__(256) void convert_x(
    const float* __restrict__ x, unsigned short* __restrict__ xb, long n)
{
    long i = ((long)blockIdx.x * 256 + threadIdx.x) * 8;
    if (i >= n) return;
    const float4* xp = (const float4*)(x + i);
    float4 a = xp[0], b = xp[1];
    uint4 o;
    o.x = f2bf(a.x) | ((unsigned)f2bf(a.y) << 16);
    o.y = f2bf(a.z) | ((unsigned)f2bf(a.w) << 16);
    o.z = f2bf(b.x) | ((unsigned)f2bf(b.y) << 16);
    o.w = f2bf(b.z) | ((unsigned)f2bf(b.w) << 16);
    *(uint4*)(xb + i) = o;
}

// ---------------------------------------------------------------------------
// gemm0_mix v3: 512 threads, 128 rows x 256 cols (8u x 32f), BK=64,
// XOR-swizzled LDS granules (bank-conflict-free b128 reads), m97-style
// barriers, LDS mix epilogue, PLANAR a1 [t][rows][512] with 64-B-run stores.
// ---------------------------------------------------------------------------
__global__ __launch_bounds__(512, 4) void gemm0_mix(
    const unsigned short* __restrict__ xb, const unsigned short* __restrict__ W0r,
    const float* __restrict__ b0, const float* __restrict__ P1n,
    unsigned short* __restrict__ a1, long plane)
{
    __shared__ __align__(16) unsigned short sm[128 * 264];   // 67584 B
    unsigned short* sA = sm;              // [128 rows][64] slab, xor-swizzled
    unsigned short* sB = sm + 128 * 64;   // [256 n][64]
    const int tid = threadIdx.x, w = tid >> 6, lane = tid & 63;
    const int flat = blockIdx.x;
    const int xcd = flat & 7, seq = flat >> 3;
    const int ng = xcd * 2 + (seq & 1);           // 2 n-groups per XCD
    const long mBase = (long)(seq >> 1) * 128;

    const int lr = lane >> 3;                 // row within 8-row chunk
    const int lg = (lane & 7) ^ lr;           // xor-swizzled source granule
    const int wm = w >> 2, wn = w & 3;
    const int r = lane & 15, q = lane >> 4;
    const int x7 = r & 7;

    facc acc[4][4];
#pragma unroll
    for (int i = 0; i < 4; i++)
#pragma unroll
        for (int j = 0; j < 4; j++) acc[i][j] = (facc){0.f, 0.f, 0.f, 0.f};

    for (int k0 = 0; k0 < 512; k0 += 64) {
        __syncthreads();
        // A: 16 chunks (8 rows x 128 B); wave w -> chunks w, w+8
#pragma unroll
        for (int i = 0; i < 2; i++) {
            const int c = w + i * 8;
            gl2lds16(xb + (mBase + c * 8 + lr) * 512 + k0 + lg * 8, sA + c * 512);
        }
        // B: 32 chunks; wave w -> 4w..4w+3
#pragma unroll
        for (int i = 0; i < 4; i++) {
            const int c = w * 4 + i;
            gl2lds16(W0r + ((long)ng * 256 + c * 8 + lr) * 512 + k0 + lg * 8,
                     sB + c * 512);
        }
        __syncthreads();
#pragma unroll
        for (int h = 0; h < 2; h++) {
            const int xg = ((h * 4 + q) ^ x7) * 8;
            bfrag aF[4], bF[4];
#pragma unroll
            for (int mt = 0; mt < 4; mt++)
                aF[mt] = *(const bfrag*)&sA[(wm * 64 + mt * 16 + r) * 64 + xg];
#pragma unroll
            for (int nt = 0; nt < 4; nt++)
                bF[nt] = *(const bfrag*)&sB[(wn * 64 + nt * 16 + r) * 64 + xg];
#pragma unroll
            for (int mt = 0; mt < 4; mt++)
#pragma unroll
                for (int nt = 0; nt < 4; nt++)
                    acc[mt][nt] = __builtin_amdgcn_mfma_f32_16x16x32_bf16(
                        aF[mt], bF[nt], acc[mt][nt], 0, 0, 0);
        }
    }

    __syncthreads();   // reuse sm as h0 tile [128 rows][264]
#pragma unroll
    for (int nt = 0; nt < 4; nt++) {
        const int cl = wn * 64 + nt * 16 + r;      // u = cl>>5, f = cl&31
        const float bv = b0[(cl >> 5) * 512 + ng * 32 + (cl & 31)];
#pragma unroll
        for (int mt = 0; mt < 4; mt++) {
            const int rowb = wm * 64 + mt * 16 + q * 4;
#pragma unroll
            for (int rg = 0; rg < 4; rg++) {
                float v = acc[mt][nt][rg] + bv;
                v = v > 0.f ? v : 0.f;
                sm[(rowb + rg) * 264 + cl] = f2bf(v);
            }
        }
    }
    __syncthreads();

    // mix: thread -> (row = tid>>2, fs = (tid&3)*8); full-sector planar stores
    float pw[64];
#pragma unroll
    for (int i = 0; i < 64; i++) pw[i] = P1n[i];   // uniform -> SGPRs
    const int row = tid >> 2, fs = (tid & 3) * 8;
    float hv[8][8];
#pragma unroll
    for (int u = 0; u < 8; u++) {
        bfrag hx = *(const bfrag*)&sm[row * 264 + u * 32 + fs];
#pragma unroll
        for (int j = 0; j < 8; j++)
            hv[u][j] = bf2f((unsigned int)(unsigned short)hx[j]);
    }
    const long rowOff = (mBase + row) * 512 + ng * 32 + fs;
#pragma unroll
    for (int t = 0; t < 8; t++) {
        float o[8];
#pragma unroll
        for (int j = 0; j < 8; j++) {
            float s = 0.f;
#pragma unroll
            for (int u = 0; u < 8; u++) s = fmaf(pw[t * 8 + u], hv[u][j], s);
            o[j] = s;
        }
        uint4 ov;
        ov.x = f2bf(o[0]) | ((unsigned)f2bf(o[1]) << 16);
        ov.y = f2bf(o[2]) | ((unsigned)f2bf(o[3]) << 16);
        ov.z = f2bf(o[4]) | ((unsigned)f2bf(o[5]) << 16);
        ov.w = f2bf(o[6]) | ((unsigned)f2bf(o[7]) << 16);
        *(uint4*)(a1 + (long)t * plane + rowOff) = ov;
    }
}

// ---------------------------------------------------------------------------
// gemm_h v3: 256 threads, 128x128, BK=64, xor-swizzled LDS, planar in/out,
// LDS-staged coalesced epilogue (256-B row runs).
// ---------------------------------------------------------------------------
__global__ __launch_bounds__(256, 4) void gemm_h(
    const unsigned short* __restrict__ a1,     // planar [u][rows][512]
    const unsigned short* __restrict__ W1t,    // [u][n][k]
    const float* __restrict__ b1,
    unsigned short* __restrict__ h1, long plane)
{
    __shared__ __align__(16) unsigned short sm[128 * 136];   // 34816 B
    unsigned short* sA = sm;              // [128][64]
    unsigned short* sB = sm + 128 * 64;   // [128][64]
    const int tid = threadIdx.x, w = tid >> 6, lane = tid & 63;
    const int flat = blockIdx.x;
    const int u = flat & 7, seq = flat >> 3;
    const int nBase = (seq & 3) * 128;
    const long mBase = (long)(seq >> 2) * 128;

    const int lr = lane >> 3, lg = (lane & 7) ^ lr;
    const int wm = w >> 1, wn = w & 1;
    const int r = lane & 15, q = lane >> 4;
    const int x7 = r & 7;

    const unsigned short* Ab = a1 + (long)u * plane;
    const unsigned short* Bb = W1t + ((long)u * 512 + nBase) * 512;

    facc acc[4][4];
#pragma unroll
    for (int i = 0; i < 4; i++)
#pragma unroll
        for (int j = 0; j < 4; j++) acc[i][j] = (facc){0.f, 0.f, 0.f, 0.f};

    for (int k0 = 0; k0 < 512; k0 += 64) {
        __syncthreads();
#pragma unroll
        for (int i = 0; i < 4; i++) {
            const int c = w * 4 + i;
            gl2lds16(Ab + (mBase + c * 8 + lr) * 512 + k0 + lg * 8, sA + c * 512);
            gl2lds16(Bb + (long)(c * 8 + lr) * 512 + k0 + lg * 8, sB + c * 512);
        }
        __syncthreads();
#pragma unroll
        for (int h = 0; h < 2; h++) {
            const int xg = ((h * 4 + q) ^ x7) * 8;
            bfrag aF[4], bF[4];
#pragma unroll
            for (int mt = 0; mt < 4; mt++)
                aF[mt] = *(const bfrag*)&sA[(wm * 64 + mt * 16 + r) * 64 + xg];
#pragma unroll
            for (int nt = 0; nt < 4; nt++)
                bF[nt] = *(const bfrag*)&sB[(wn * 64 + nt * 16 + r) * 64 + xg];
#pragma unroll
            for (int mt = 0; mt < 4; mt++)
#pragma unroll
                for (int nt = 0; nt < 4; nt++)
                    acc[mt][nt] = __builtin_amdgcn_mfma_f32_16x16x32_bf16(
                        aF[mt], bF[nt], acc[mt][nt], 0, 0, 0);
        }
    }

    __syncthreads();   // reuse sm as C tile [128][136]
#pragma unroll
    for (int nt = 0; nt < 4; nt++) {
        const int col = wn * 64 + nt * 16 + r;
        const float bv = b1[u * 512 + nBase + col];
#pragma unroll
        for (int mt = 0; mt < 4; mt++) {
            const int rowb = wm * 64 + mt * 16 + q * 4;
#pragma unroll
            for (int rg = 0; rg < 4; rg++) {
                float v = acc[mt][nt][rg] + bv;
                v = v > 0.f ? v : 0.f;
                sm[(rowb + rg) * 136 + col] = f2bf(v);
            }
        }
    }
    __syncthreads();

    // coalesced write: 16 lanes x 16 B = 256-B full row runs
    unsigned short* Cb = h1 + (long)u * plane + mBase * 512 + nBase;
#pragma unroll
    for (int it = 0; it < 8; it++) {
        const int g = tid + it * 256;
        const int row = g >> 4, gr = g & 15;
        *(uint4*)(Cb + (long)row * 512 + gr * 8) = *(const uint4*)&sm[row * 136 + gr * 8];
    }
}

// ---------------------------------------------------------------------------
// gemm_out v3: split-K=2 (kc over 4 h1-planes each), 64 rows x 64 cols,
// BK=64, xor-swizzle, fp32 partial with 64-B-run stores.
// ---------------------------------------------------------------------------
__global__ __launch_bounds__(256, 4) void gemm_out(
    const unsigned short* __restrict__ h1,     // planar [f][rows][512]
    const unsigned short* __restrict__ Bt,     // Woutt [64 c][4096]
    float* __restrict__ partial, long plane, int Bc)
{
    __shared__ __align__(16) unsigned short sA[64 * 64];
    __shared__ __align__(16) unsigned short sB[64 * 64];
    const int tid = threadIdx.x, w = tid >> 6, lane = tid & 63;
    const int flat = blockIdx.x;
    const int kc = flat & 1;
    const long mBase = (long)(flat >> 1) * 64;

    const int lr = lane >> 3, lg = (lane & 7) ^ lr;
    const int wm = w >> 1, wn = w & 1;
    const int r = lane & 15, q = lane >> 4;
    const int x7 = r & 7;

    facc acc[2][2];
#pragma unroll
    for (int i = 0; i < 2; i++)
#pragma unroll
        for (int j = 0; j < 2; j++) acc[i][j] = (facc){0.f, 0.f, 0.f, 0.f};

    for (int it = 0; it < 32; it++) {
        const int u = kc * 4 + (it >> 3);
        const int kk = (it & 7) * 64;
        __syncthreads();
#pragma unroll
        for (int i = 0; i < 2; i++) {
            const int c = w * 2 + i;
            gl2lds16(h1 + (long)u * plane + (mBase + c * 8 + lr) * 512 + kk + lg * 8,
                     sA + c * 512);
            gl2lds16(Bt + (long)(c * 8 + lr) * 4096 + u * 512 + kk + lg * 8,
                     sB + c * 512);
        }
        __syncthreads();
#pragma unroll
        for (int h = 0; h < 2; h++) {
            const int xg = ((h * 4 + q) ^ x7) * 8;
            bfrag aF[2], bF[2];
#pragma unroll
            for (int mt = 0; mt < 2; mt++)
                aF[mt] = *(const bfrag*)&sA[(wm * 32 + mt * 16 + r) * 64 + xg];
#pragma unroll
            for (int nt = 0; nt < 2; nt++)
                bF[nt] = *(const bfrag*)&sB[(wn * 32 + nt * 16 + r) * 64 + xg];
#pragma unroll
            for (int mt = 0; mt < 2; mt++)
#pragma unroll
                for (int nt = 0; nt < 2; nt++)
                    acc[mt][nt] = __builtin_amdgcn_mfma_f32_16x16x32_bf16(
                        aF[mt], bF[nt], acc[mt][nt], 0, 0, 0);
        }
    }

    float* pb = partial + ((long)kc * Bc + mBase) * 64;
#pragma unroll
    for (int nt = 0; nt < 2; nt++) {
        const int col = wn * 32 + nt * 16 + r;
#pragma unroll
        for (int mt = 0; mt < 2; mt++) {
#pragma unroll
            for (int rg = 0; rg < 4; rg++) {
                const int row = wm * 32 + mt * 16 + q * 4 + rg;
                pb[(long)row * 64 + col] = acc[mt][nt][rg];
            }
        }
    }
}

// ---------------------------------------------------------------------------
// reduce_out: out[row][c] = partial[0]+partial[1] + cconst[c]
// ---------------------------------------------------------------------------
__global__ __launch_bounds__(256) void reduce_out(
    const float* __restrict__ partial, const float* __restrict__ cconst,
    float* __restrict__ out, int Bc)
{
    const long flat = (long)blockIdx.x * 256 + threadIdx.x;
    const long row = flat >> 2;
    const int cg = (int)(flat & 3) * 16;
    float s[16];
#pragma unroll
    for (int j = 0; j < 16; j++) s[j] = 0.f;
#pragma unroll
    for (int kc = 0; kc < 2; kc++) {
        const float4* p = (const float4*)(partial + ((long)kc * Bc + row) * 64 + cg);
#pragma unroll
        for (int v4 = 0; v4 < 4; v4++) {
            float4 v = p[v4];
            s[v4 * 4 + 0] += v.x; s[v4 * 4 + 1] += v.y;
            s[v4 * 4 + 2] += v.z; s[v4 * 4 + 3] += v.w;
        }
    }
#pragma unroll
    for (int j = 0; j < 16; j++) {
        const int c = cg + j;
        if (c < NC_) out[row * NC_ + c] = s[j] + cconst[c];
    }
}

// ---------------------------------------------------------------------------
extern "C" void kernel_launch(void* const* d_in, const int* in_sizes, int n_in,
                              void* d_out, int out_size, void* d_ws, size_t ws_size,
                              hipStream_t stream)
{
    const float* x  = (const float*)d_in[0];
    const float* p1 = (const float*)d_in[1];
    const float* p2 = (const float*)d_in[2];
    const float* pf = (const float*)d_in[3];
    const float* W0 = (const float*)d_in[4];
    const float* b0 = (const float*)d_in[5];
    const float* W1 = (const float*)d_in[6];
    const float* b1 = (const float*)d_in[7];
    const float* W2 = (const float*)d_in[8];
    const float* b2 = (const float*)d_in[9];
    float* out = (float*)d_out;

    char* ws = (char*)d_ws;
    size_t off = 0;
    auto alloc = [&](size_t bytes) -> void* {
        void* p = ws + off;
        off += (bytes + 255) & ~(size_t)255;
        return p;
    };
    float* P1n    = (float*)alloc(64 * sizeof(float));
    float* P2n    = (float*)alloc(64 * sizeof(float));
    float* wfin   = (float*)alloc(8 * sizeof(float));
    float* cconst = (float*)alloc(64 * sizeof(float));
    unsigned short* W0r   = (unsigned short*)alloc((size_t)4096 * 512 * 2);
    unsigned short* W1t   = (unsigned short*)alloc((size_t)U_ * 512 * 512 * 2);
    unsigned short* Woutt = (unsigned short*)alloc((size_t)64 * 4096 * 2);
    unsigned short* xb    = (unsigned short*)alloc((size_t)B_ * 512 * 2);

    // a1 + h1 planar (8 planes x Bc x 512 bf16 each) + fp32 partial (2 x Bc x 64)
    size_t remain = ws_size > off ? ws_size - off : 0;
    int Bc = 2048;
    for (int cand = B_; cand >= 2048; cand >>= 1) {
        size_t need = 2ull * 8 * cand * 512 * 2 + 2ull * cand * 64 * 4 + 1024;
        if (need <= remain) { Bc = cand; break; }
    }
    unsigned short* a1 = (unsigned short*)alloc(8ull * Bc * 512 * 2);
    unsigned short* h1 = (unsigned short*)alloc(8ull * Bc * 512 * 2);
    float* partial     = (float*)alloc(2ull * Bc * 64 * 4);

    prep_kernel<<<1, 64, 0, stream>>>(p1, p2, pf, b2, P1n, P2n, wfin, cconst);
    reorder_w0<<<dim3(16, 16, 8), 256, 0, stream>>>(W0, W0r);
    transpose_w<<<dim3(16, 16, 8), 256, 0, stream>>>(W1, W1t);
    wout_build<<<dim3(1024), 256, 0, stream>>>(W2, P2n, wfin, Woutt);
    convert_x<<<dim3(B_ * 512 / 8 / 256), 256, 0, stream>>>(x, xb, (long)B_ * 512);

    const int Mb = Bc / 128;
    const long plane = (long)Bc * 512;
    for (int bb = 0; bb < B_; bb += Bc) {
        gemm0_mix<<<dim3(16 * Mb), 512, 0, stream>>>(
            xb + (long)bb * 512, W0r, b0, P1n, a1, plane);
        gemm_h<<<dim3(32 * Mb), 256, 0, stream>>>(a1, W1t, b1, h1, plane);
        gemm_out<<<dim3(2 * (Bc / 64)), 256, 0, stream>>>(h1, Woutt, partial, plane, Bc);
        reduce_out<<<dim3(Bc / 64), 256, 0, stream>>>(
            partial, cconst, out + (long)bb * NC_, Bc);
    }
}